// Round 11
// baseline (207.299 us; speedup 1.0000x reference)
//
#include <hip/hip_runtime.h>

#define NF    25     // input features per row
#define NPAIR 300    // upper-triangle pairs (25*24/2)
#define NCOL  425    // output cols: 25*5 + 300
#define ROWS  8      // rows per chunk
#define BLK   512    // 8 waves; 4 blocks/CU = 32 waves (full occupancy)
#define TILE4N 850                // float4s per chunk (13600 B)
#define NP_TOT (ROWS * NPAIR)     // 2400 pair products per chunk
#define KFULL  (NP_TOT / BLK)     // 4 full passes
#define KREM   (NP_TOT - KFULL * BLK) // 352 tail threads

typedef float f32x4 __attribute__((ext_vector_type(4)));
typedef unsigned int u32;

__global__ __launch_bounds__(BLK, 8) void feat_expand_kernel(
    const float* __restrict__ x, float* __restrict__ out,
    int nrows, int nchunks) {
  // Double-buffered pipeline (R10 structure, BLK=512):
  // window = { C-store(chunk) from tile[par], B-compute(chunk+G) into
  //   tile[par^1] from xs[par^1], A-load(chunk+2G) into xs[par] }
  __shared__ f32x4 tile4[2][TILE4N];        // 27200 B
  __shared__ float xs[2][ROWS * NF];        // 1600 B

  const int tid = threadIdx.x;
  const int r200 = tid / NF, i200 = tid - r200 * NF;

  // Hoisted static B2 descriptors (chunk-independent)
  u32 ab[KFULL + 1];
  u32 ti[KFULL + 1];
#pragma unroll
  for (int k = 0; k <= KFULL; ++k) {
    int p = tid + k * BLK;
    if (p >= NP_TOT) p = 0;                 // dummy; predicated off at use
    const int r = p / NPAIR;
    const int q = p - r * NPAIR;
    int rem = q, i = 0;
    while (rem >= (NF - 1 - i)) { rem -= (NF - 1 - i); ++i; }
    ab[k] = (u32)(r * NF + i) | ((u32)(r * NF + i + 1 + rem) << 16);
    ti[k] = (u32)(r * NCOL + 5 * NF + q);
  }

  const long long G  = gridDim.x;
  const long long c0 = blockIdx.x;

  auto stageA = [&](int b, long long cc) {   // x(chunk cc) -> xs[b]
    if (tid < ROWS * NF) {
      const long long rowbase = cc * ROWS;
      float v = 0.0f;
      if (rowbase + r200 < nrows) v = x[rowbase * NF + tid];
      xs[b][tid] = v;
    }
  };
  auto stageB = [&](int bt, int bx) {        // tile[bt] <- features(xs[bx])
    float* tile = (float*)tile4[bt];
    if (tid < ROWS * NF) {
      const float v = xs[bx][tid];
      float* tr = &tile[r200 * NCOL];
      const float ax = fabsf(v) + 1e-10f;
      const float l2 = __builtin_amdgcn_logf(ax);        // v_log_f32: log2
      tr[i200]        = v;                               // identity
      tr[NF + i200]   = v * v;                           // square
      tr[2*NF + i200] = l2 * 0.69314718055994530942f;    // ln = log2*ln2
      tr[3*NF + i200] = sqrtf(ax);                       // v_sqrt_f32
      tr[4*NF + i200] = __builtin_amdgcn_exp2f(l2 * (1.0f/3.0f)); // cbrt
    }
#pragma unroll
    for (int k = 0; k <= KFULL; ++k) {
      if (k < KFULL || tid < KREM) {
        const u32 d = ab[k];
        tile[ti[k]] = xs[bx][d & 0xFFFF] * xs[bx][d >> 16];
      }
    }
  };

  // Prologue: fill pipeline (tile[0] = chunk c0; xs[1] = chunk c0+G)
  if (c0 < nchunks) stageA(0, c0);
  __syncthreads();
  if (c0 < nchunks) stageB(0, 0);
  if (c0 + G < nchunks) stageA(1, c0 + G);
  __syncthreads();

  int par = 0;
  for (long long chunk = c0; chunk < nchunks; chunk += G, par ^= 1) {
    // C: store chunk from tile[par] (nt, float4, 850 = 1*512 + 338)
    const long long rowbase = chunk * ROWS;
    const long long remr = nrows - rowbase;
    const int rows_here = (int)(remr < ROWS ? remr : ROWS);
    if (rows_here == ROWS) {
      f32x4* __restrict__ o4 = (f32x4*)(out + rowbase * NCOL);
#pragma unroll
      for (int k = 0; k < 2; ++k) {
        const int v4 = tid + k * BLK;
        if (k < 1 || v4 < TILE4N)
          __builtin_nontemporal_store(tile4[par][v4], &o4[v4]);
      }
    } else {  // tail chunk (not hit when nrows % ROWS == 0)
      const float* tile = (const float*)tile4[par];
      const int total = rows_here * NCOL;
      for (int o = tid; o < total; o += BLK)
        out[rowbase * NCOL + o] = tile[o];
    }

    // B: compute next chunk's tile; A: load chunk after next. Disjoint buffers.
    if (chunk + G < nchunks)     stageB(par ^ 1, par ^ 1);
    if (chunk + 2*G < nchunks)   stageA(par, chunk + 2*G);
    __syncthreads();
  }
}

extern "C" void kernel_launch(void* const* d_in, const int* in_sizes, int n_in,
                              void* d_out, int out_size, void* d_ws, size_t ws_size,
                              hipStream_t stream) {
  const float* x = (const float*)d_in[0];
  float* out = (float*)d_out;

  const int nrows = in_sizes[0] / NF;                 // 524288
  const int nchunks = (nrows + ROWS - 1) / ROWS;      // 65536
  const int grid = nchunks < 4096 ? nchunks : 4096;

  feat_expand_kernel<<<grid, BLK, 0, stream>>>(x, out, nrows, nchunks);
}